// Round 3
// baseline (792.523 us; speedup 1.0000x reference)
//
#include <hip/hip_runtime.h>
#include <math.h>

// ---------------------------------------------------------------------------
// B=256, S=512, D=768, H_att=128, topk=12, proj hidden=256, rows=5, cols=12.
//
// Pipeline:
//   K0 prep: att_w1 -> split-bf16 (hi/lo) MFMA B-fragments + k-major fp32
//            repack (w1q, for exact rescore); proj_w1 -> k-major transpose
//            (w1p, coalesced projector reads).
//   K1 score_mfma: approx scores via 3-pass split-bf16 MFMA. Each wave covers
//            the FULL N=128 and M=32 rows; A-fragments loaded straight from
//            global into registers (no LDS, no barriers). HBM-bound.
//   K2 select: per batch: barrier-free per-wave top-16 + single-wave merge ->
//            exact fp32 rescore of 16 candidates -> top-12 (tie: smallest
//            index) -> sort by index -> fp32 projector (exact GELU, candidate-
//            split waves, coalesced w1p) -> LayerNorm.
// ---------------------------------------------------------------------------
#define B_BATCH 256
#define S_LEN   512
#define D_DIM   768
#define H_ATT   128
#define TOPK    12
#define NCAND   16
#define H_PROJ  256
#define N_ROWS  5
#define N_COLS  12

typedef __bf16 bf16x8 __attribute__((ext_vector_type(8)));
typedef float  f32x4  __attribute__((ext_vector_type(4)));

// ws layout (bytes):
//   [0,        524288)   approx scores, 131072 f32
//   [524288,   720896)   att_w1 hi bf16 frags: [((nt*24+kt)*64+lane)*8+j]
//   [720896,   917504)   att_w1 lo bf16 frags (same layout)
//   [917504,  1310720)   w1q: f32[(k4*128+n)*4+i] = att_w1[n][4k4+i]
//   [1310720, 2097152)   w1p: f32[(k4*256+j)*4+i] = proj_w1[j][4k4+i]
#define WS_SCORES 0
#define WS_WHI    524288
#define WS_WLO    720896
#define WS_W1Q    917504
#define WS_W1P    1310720

// ===========================================================================
// K0: prep (1536 blocks x 256 threads, one element each)
// ===========================================================================
__global__ __launch_bounds__(256) void prep_kernel(
    const float* __restrict__ w1,   // att_w1 [128,768]
    const float* __restrict__ pw1,  // proj_w1 [256,768]
    __bf16* __restrict__ whi, __bf16* __restrict__ wlo,
    float* __restrict__ w1q, float* __restrict__ w1p)
{
    int id = blockIdx.x * 256 + threadIdx.x;   // 0..393215
    if (id < 98304) {
        // split-bf16 B-fragment build: id = ((nt*24+kt)*64+lane)*8+j
        int j    = id & 7;
        int lane = (id >> 3) & 63;
        int rest = id >> 9;            // 0..191
        int kt   = rest % 24;
        int nt   = rest / 24;
        int n = nt * 16 + (lane & 15);
        int k = kt * 32 + (lane >> 4) * 8 + j;
        float f = w1[n * D_DIM + k];
        __bf16 h = (__bf16)f;
        whi[id] = h;
        wlo[id] = (__bf16)(f - (float)h);
    } else if (id < 196608) {
        // w1q repack: e2 = (k4*128+n)*4+i
        int e2 = id - 98304;
        int i  = e2 & 3;
        int n  = (e2 >> 2) & 127;
        int k4 = e2 >> 9;
        w1q[e2] = w1[n * D_DIM + k4 * 4 + i];
    } else {
        // w1p transpose: e = (k4*256+j)*4+i
        int e  = id - 196608;
        int i  = e & 3;
        int j  = (e >> 2) & 255;
        int k4 = e >> 10;
        w1p[e] = pw1[j * D_DIM + k4 * 4 + i];
    }
}

// ===========================================================================
// K1: approx scores, register-direct MFMA. 1024 blocks x 256 threads;
//     each wave: M=32 rows (2 m-frags) x full N=128 (8 n-tiles), no LDS.
// ===========================================================================
__device__ inline void split8(float4 a, float4 b, bf16x8& hi, bf16x8& lo) {
    float v[8] = {a.x, a.y, a.z, a.w, b.x, b.y, b.z, b.w};
#pragma unroll
    for (int i = 0; i < 8; ++i) {
        __bf16 h = (__bf16)v[i];
        hi[i] = h;
        lo[i] = (__bf16)(v[i] - (float)h);
    }
}

__global__ __launch_bounds__(256) void score_mfma(
    const float*  __restrict__ th,    // [131072, 768]
    const __bf16* __restrict__ whi,   // B-frags hi
    const __bf16* __restrict__ wlo,   // B-frags lo
    const float*  __restrict__ b1,    // [128]
    const float*  __restrict__ w2,    // [128]
    float* __restrict__ scores)       // [131072]
{
    const int ln = threadIdx.x & 63;
    const int gw = (blockIdx.x * 256 + threadIdx.x) >> 6;  // global wave 0..4095

    const size_t row0 = (size_t)gw * 32 + (ln & 15);
    const float* pa0 = th + row0 * D_DIM + (ln >> 4) * 8;
    const float* pa1 = pa0 + 16 * D_DIM;

    f32x4 acc[2][8];
    const f32x4 z = {0.f, 0.f, 0.f, 0.f};
#pragma unroll
    for (int i = 0; i < 2; ++i)
#pragma unroll
        for (int j = 0; j < 8; ++j) acc[i][j] = z;

    // software-pipelined A loads (registers only)
    float4 c00 = *(const float4*)(pa0);
    float4 c01 = *(const float4*)(pa0 + 4);
    float4 c10 = *(const float4*)(pa1);
    float4 c11 = *(const float4*)(pa1 + 4);

    for (int kt = 0; kt < 24; ++kt) {
        const int ktn = (kt < 23) ? kt + 1 : 23;
        float4 n00 = *(const float4*)(pa0 + ktn * 32);
        float4 n01 = *(const float4*)(pa0 + ktn * 32 + 4);
        float4 n10 = *(const float4*)(pa1 + ktn * 32);
        float4 n11 = *(const float4*)(pa1 + ktn * 32 + 4);

        bf16x8 ah0, al0, ah1, al1;
        split8(c00, c01, ah0, al0);
        split8(c10, c11, ah1, al1);

        const __bf16* bhp = whi + ((size_t)kt * 64 + ln) * 8;
        const __bf16* blp = wlo + ((size_t)kt * 64 + ln) * 8;
#pragma unroll
        for (int nt = 0; nt < 8; ++nt) {
            bf16x8 bh = *(const bf16x8*)(bhp + (size_t)nt * 24 * 512);
            bf16x8 bl = *(const bf16x8*)(blp + (size_t)nt * 24 * 512);
            acc[0][nt] = __builtin_amdgcn_mfma_f32_16x16x32_bf16(ah0, bh, acc[0][nt], 0, 0, 0);
            acc[0][nt] = __builtin_amdgcn_mfma_f32_16x16x32_bf16(al0, bh, acc[0][nt], 0, 0, 0);
            acc[0][nt] = __builtin_amdgcn_mfma_f32_16x16x32_bf16(ah0, bl, acc[0][nt], 0, 0, 0);
            acc[1][nt] = __builtin_amdgcn_mfma_f32_16x16x32_bf16(ah1, bh, acc[1][nt], 0, 0, 0);
            acc[1][nt] = __builtin_amdgcn_mfma_f32_16x16x32_bf16(al1, bh, acc[1][nt], 0, 0, 0);
            acc[1][nt] = __builtin_amdgcn_mfma_f32_16x16x32_bf16(ah1, bl, acc[1][nt], 0, 0, 0);
        }
        c00 = n00; c01 = n01; c10 = n10; c11 = n11;
    }

    // epilogue: s = sum_n tanh(pre + b1[n]) * w2[n]; reduce over the 16 cols
    const int col = ln & 15;
    float b1v[8], w2v[8];
#pragma unroll
    for (int nt = 0; nt < 8; ++nt) {
        b1v[nt] = b1[nt * 16 + col];
        w2v[nt] = w2[nt * 16 + col];
    }
#pragma unroll
    for (int mf = 0; mf < 2; ++mf)
#pragma unroll
        for (int r = 0; r < 4; ++r) {
            float s = 0.f;
#pragma unroll
            for (int nt = 0; nt < 8; ++nt)
                s += tanhf(acc[mf][nt][r] + b1v[nt]) * w2v[nt];
            s += __shfl_xor(s, 1, 64);
            s += __shfl_xor(s, 2, 64);
            s += __shfl_xor(s, 4, 64);
            s += __shfl_xor(s, 8, 64);
            if (col == 0)
                scores[(size_t)gw * 32 + mf * 16 + (ln >> 4) * 4 + r] = s;
        }
}

// ===========================================================================
// K2: per batch select + project. 256 blocks x 256 threads.
// ===========================================================================
__global__ __launch_bounds__(256) void select_kernel(
    const float* __restrict__ th,      // [B*S, 768]
    const int*   __restrict__ mask,    // [B*S]
    const float* __restrict__ ascores, // approx scores [B*S]
    const float* __restrict__ w1q,     // k-major att_w1
    const float* __restrict__ ab1,     // att_b1 [128]
    const float* __restrict__ aw2,     // att_w2 [128]
    const float* __restrict__ w1p,     // k-major proj_w1
    const float* __restrict__ pb1,     // proj_b1 [256]
    const float* __restrict__ pw2,     // [5, 256]
    const float* __restrict__ pb2,     // [5]
    const float* __restrict__ gamma,   // [60]
    const float* __restrict__ beta,    // [60]
    float* __restrict__ out)           // [B, 5, 12]
{
    const int b   = blockIdx.x;
    const int tid = threadIdx.x;
    const int wv  = tid >> 6;
    const int ln  = tid & 63;

    __shared__ float4 xc[NCAND][192];          // 48KB candidate rows (fp32)
    __shared__ unsigned long long wtop[64];
    __shared__ int   cand[NCAND];
    __shared__ float redW[4][8];
    __shared__ float exact_sc[NCAND];
    __shared__ int   sel_slot[TOPK];
    __shared__ float gbuf[TOPK][H_PROJ + 1];
    __shared__ float feat[N_ROWS * N_COLS];
    __shared__ float stats[2];

    const float NEG_MIN = -3.402823466e38f;    // finfo(float32).min

    // --- barrier-free per-wave top-16 over 128 scores (2 keys/lane) ---
    {
        int i0 = wv * 128 + ln, i1 = i0 + 64;
        float v0 = ascores[(size_t)b * S_LEN + i0];
        if (mask[(size_t)b * S_LEN + i0] == 0) v0 = NEG_MIN;
        float v1 = ascores[(size_t)b * S_LEN + i1];
        if (mask[(size_t)b * S_LEN + i1] == 0) v1 = NEG_MIN;
        unsigned k0 = __float_as_uint(v0);
        k0 = ((int)k0 >= 0) ? (k0 | 0x80000000u) : ~k0;
        unsigned k1 = __float_as_uint(v1);
        k1 = ((int)k1 >= 0) ? (k1 | 0x80000000u) : ~k1;
        unsigned long long p0 = ((unsigned long long)k0 << 32) | (0xFFFFFFFFu - (unsigned)i0);
        unsigned long long p1 = ((unsigned long long)k1 << 32) | (0xFFFFFFFFu - (unsigned)i1);
        for (int it = 0; it < NCAND; ++it) {
            unsigned long long m = p0 > p1 ? p0 : p1;
#pragma unroll
            for (int s = 1; s <= 32; s <<= 1) {
                unsigned long long o = __shfl_xor(m, s, 64);
                if (o > m) m = o;
            }
            if (ln == 0) wtop[wv * 16 + it] = m;
            if (p0 == m) p0 = 0ull;
            else if (p1 == m) p1 = 0ull;
        }
    }
    __syncthreads();
    // --- single-wave merge of 64 keys -> global top-16 (desc score order) ---
    if (wv == 0) {
        unsigned long long q = wtop[ln];
        for (int it = 0; it < NCAND; ++it) {
            unsigned long long m = q;
#pragma unroll
            for (int s = 1; s <= 32; s <<= 1) {
                unsigned long long o = __shfl_xor(m, s, 64);
                if (o > m) m = o;
            }
            if (ln == 0) cand[it] = (int)(0xFFFFFFFFu - (unsigned)(m & 0xFFFFFFFFu));
            if (q == m) q = 0ull;
        }
    }
    __syncthreads();

    // --- stage candidate rows into LDS (fp32, float4) ---
#pragma unroll
    for (int i = 0; i < 12; ++i) {
        int f = tid + 256 * i;             // 0..3071
        int c = f / 192, k4 = f % 192;
        xc[c][k4] = *(const float4*)(th + ((size_t)b * S_LEN + cand[c]) * D_DIM + k4 * 4);
    }
    __syncthreads();

    // --- exact fp32 rescore of 16 candidates ---
    {
        const int n = tid & 127;
        const int h = tid >> 7;
        float accs[8];
#pragma unroll
        for (int ci = 0; ci < 8; ++ci) accs[ci] = 0.f;
        for (int k4 = 0; k4 < 192; ++k4) {
            float4 w = *(const float4*)(w1q + (size_t)(k4 * 128 + n) * 4);
#pragma unroll
            for (int ci = 0; ci < 8; ++ci) {
                float4 x = xc[2 * ci + h][k4];
                accs[ci] += w.x * x.x + w.y * x.y + w.z * x.z + w.w * x.w;
            }
        }
        float b1n = ab1[n], w2n = aw2[n];
#pragma unroll
        for (int ci = 0; ci < 8; ++ci) {
            float val = tanhf(accs[ci] + b1n) * w2n;
            val += __shfl_xor(val, 1, 64);
            val += __shfl_xor(val, 2, 64);
            val += __shfl_xor(val, 4, 64);
            val += __shfl_xor(val, 8, 64);
            val += __shfl_xor(val, 16, 64);
            val += __shfl_xor(val, 32, 64);
            if (ln == 0) redW[wv][ci] = val;
        }
    }
    __syncthreads();
    if (tid < NCAND) {
        int c = tid;
        float ex = (c & 1) ? (redW[2][c >> 1] + redW[3][c >> 1])
                           : (redW[0][c >> 1] + redW[1][c >> 1]);
        if (mask[(size_t)b * S_LEN + cand[c]] == 0) ex = -INFINITY;
        exact_sc[c] = ex;
    }
    __syncthreads();

    // --- exact top-12 among candidates (tie -> smallest token index), sort ---
    if (tid == 0) {
        unsigned picked = 0;
        int slots[TOPK];
        for (int it = 0; it < TOPK; ++it) {
            float best = -INFINITY; int bslot = -1; int bidx = 1 << 30;
            for (int c = 0; c < NCAND; ++c) {
                if (picked & (1u << c)) continue;
                float e = exact_sc[c]; int idx = cand[c];
                if (e > best || (e == best && idx < bidx)) { best = e; bslot = c; bidx = idx; }
            }
            picked |= 1u << bslot;
            slots[it] = bslot;
        }
        for (int i = 1; i < TOPK; ++i) {
            int s = slots[i], key = cand[s], j = i - 1;
            while (j >= 0 && cand[slots[j]] > key) { slots[j + 1] = slots[j]; --j; }
            slots[j + 1] = s;
        }
        for (int t = 0; t < TOPK; ++t) sel_slot[t] = slots[t];
    }
    __syncthreads();

    // --- projector: wave wv owns candidates 3wv..3wv+2; lane covers 4 cols ---
    {
        const int c0 = wv * 3;
        int s0 = sel_slot[c0], s1 = sel_slot[c0 + 1], s2 = sel_slot[c0 + 2];
        float accp[4][3];
#pragma unroll
        for (int cc = 0; cc < 4; ++cc) {
            float bj = pb1[cc * 64 + ln];
            accp[cc][0] = bj; accp[cc][1] = bj; accp[cc][2] = bj;
        }
        for (int k4 = 0; k4 < 192; ++k4) {
            float4 x0 = xc[s0][k4];
            float4 x1 = xc[s1][k4];
            float4 x2 = xc[s2][k4];
#pragma unroll
            for (int cc = 0; cc < 4; ++cc) {
                float4 w = *(const float4*)(w1p + (size_t)(k4 * 256 + cc * 64 + ln) * 4);
                accp[cc][0] += w.x * x0.x + w.y * x0.y + w.z * x0.z + w.w * x0.w;
                accp[cc][1] += w.x * x1.x + w.y * x1.y + w.z * x1.z + w.w * x1.w;
                accp[cc][2] += w.x * x2.x + w.y * x2.y + w.z * x2.z + w.w * x2.w;
            }
        }
#pragma unroll
        for (int cc = 0; cc < 4; ++cc)
#pragma unroll
            for (int c = 0; c < 3; ++c) {
                float hh = accp[cc][c];
                gbuf[c0 + c][cc * 64 + ln] =
                    0.5f * hh * (1.0f + erff(hh * 0.70710678118654752f));
            }
    }
    __syncthreads();

    // --- f @ pw2^T + pb2 ---
    if (tid < TOPK * N_ROWS) {
        int t = tid / N_ROWS, r = tid % N_ROWS;
        float s = pb2[r];
        for (int j = 0; j < H_PROJ; ++j) s += gbuf[t][j] * pw2[r * H_PROJ + j];
        feat[r * N_COLS + t] = s;
    }
    __syncthreads();

    // --- LayerNorm over 60 elements ---
    if (tid == 0) {
        float sum = 0.f;
        for (int i = 0; i < N_ROWS * N_COLS; ++i) sum += feat[i];
        float mean = sum / 60.f;
        float sq = 0.f;
        for (int i = 0; i < N_ROWS * N_COLS; ++i) { float d = feat[i] - mean; sq += d * d; }
        stats[0] = mean;
        stats[1] = sq / 60.f;
    }
    __syncthreads();
    if (tid < N_ROWS * N_COLS) {
        float x = feat[tid];
        out[(size_t)b * 60 + tid] =
            gamma[tid] * (x - stats[0]) * rsqrtf(stats[1] + 1e-5f) + beta[tid];
    }
}

// ===========================================================================
extern "C" void kernel_launch(void* const* d_in, const int* in_sizes, int n_in,
                              void* d_out, int out_size, void* d_ws, size_t ws_size,
                              hipStream_t stream) {
    const float* th   = (const float*)d_in[0];
    const int*   mask = (const int*)  d_in[1];
    const float* aw1  = (const float*)d_in[2];
    const float* ab1  = (const float*)d_in[3];
    const float* aw2  = (const float*)d_in[4];
    // d_in[5] att_b2: constant shift — irrelevant for top-k ordering
    const float* pw1  = (const float*)d_in[6];
    const float* pb1  = (const float*)d_in[7];
    const float* pw2  = (const float*)d_in[8];
    const float* pb2  = (const float*)d_in[9];
    const float* gam  = (const float*)d_in[10];
    const float* bet  = (const float*)d_in[11];
    float* out = (float*)d_out;

    char* ws = (char*)d_ws;
    float*  scores = (float*)(ws + WS_SCORES);
    __bf16* whi    = (__bf16*)(ws + WS_WHI);
    __bf16* wlo    = (__bf16*)(ws + WS_WLO);
    float*  w1q    = (float*)(ws + WS_W1Q);
    float*  w1p    = (float*)(ws + WS_W1P);

    hipLaunchKernelGGL(prep_kernel, dim3(1536), dim3(256), 0, stream,
                       aw1, pw1, whi, wlo, w1q, w1p);
    hipLaunchKernelGGL(score_mfma, dim3(1024), dim3(256), 0, stream,
                       th, whi, wlo, ab1, aw2, scores);
    hipLaunchKernelGGL(select_kernel, dim3(B_BATCH), dim3(256), 0, stream,
                       th, mask, scores, w1q, ab1, aw2,
                       w1p, pb1, pw2, pb2, gam, bet, out);
}

// Round 4
// 727.694 us; speedup vs baseline: 1.0891x; 1.0891x over previous
//
#include <hip/hip_runtime.h>
#include <math.h>

// ---------------------------------------------------------------------------
// B=256, S=512, D=768, H_att=128, topk=12, proj hidden=256, rows=5, cols=12.
//
// Pipeline:
//   K0 prep: att_w1 -> split-bf16 (hi/lo) MFMA B-fragments + k-major fp32
//            repack (w1q); proj_w1 -> k-major transpose (w1p).
//   K1 score_mfma: approx scores via 3-pass split-bf16 MFMA. B-frags staged
//            per-block into double-buffered LDS via global_load_lds(16);
//            A loaded register-direct from HBM with 1-kt prefetch.
//   K2 select: per batch: barrier-free top-16 -> exact fp32 rescore ->
//            top-12 (tie: smallest index) -> sort -> fp32 projector
//            (column-per-thread, LDS-broadcast x, coalesced w1p) -> LayerNorm.
// ---------------------------------------------------------------------------
#define B_BATCH 256
#define S_LEN   512
#define D_DIM   768
#define H_ATT   128
#define TOPK    12
#define NCAND   16
#define H_PROJ  256
#define N_ROWS  5
#define N_COLS  12

typedef __bf16 bf16x8 __attribute__((ext_vector_type(8)));
typedef float  f32x4  __attribute__((ext_vector_type(4)));

#define GLOBAL_AS __attribute__((address_space(1)))
#define LDS_AS    __attribute__((address_space(3)))

// ws layout (bytes):
//   [0,        524288)   approx scores, 131072 f32
//   [524288,   720896)   att_w1 hi bf16 frags: [((nt*24+kt)*64+lane)*8+j]
//   [720896,   917504)   att_w1 lo bf16 frags (same layout)
//   [917504,  1310720)   w1q: f32[(k4*128+n)*4+i] = att_w1[n][4k4+i]
//   [1310720, 2097152)   w1p: f32[(k4*256+j)*4+i] = proj_w1[j][4k4+i]
#define WS_SCORES 0
#define WS_WHI    524288
#define WS_WLO    720896
#define WS_W1Q    917504
#define WS_W1P    1310720

// ===========================================================================
// K0: prep (1536 blocks x 256 threads, one element each)
// ===========================================================================
__global__ __launch_bounds__(256) void prep_kernel(
    const float* __restrict__ w1,   // att_w1 [128,768]
    const float* __restrict__ pw1,  // proj_w1 [256,768]
    __bf16* __restrict__ whi, __bf16* __restrict__ wlo,
    float* __restrict__ w1q, float* __restrict__ w1p)
{
    int id = blockIdx.x * 256 + threadIdx.x;   // 0..393215
    if (id < 98304) {
        // split-bf16 B-fragment build: id = ((nt*24+kt)*64+lane)*8+j
        int j    = id & 7;
        int lane = (id >> 3) & 63;
        int rest = id >> 9;            // 0..191
        int kt   = rest % 24;
        int nt   = rest / 24;
        int n = nt * 16 + (lane & 15);
        int k = kt * 32 + (lane >> 4) * 8 + j;
        float f = w1[n * D_DIM + k];
        __bf16 h = (__bf16)f;
        whi[id] = h;
        wlo[id] = (__bf16)(f - (float)h);
    } else if (id < 196608) {
        // w1q repack: e2 = (k4*128+n)*4+i
        int e2 = id - 98304;
        int i  = e2 & 3;
        int n  = (e2 >> 2) & 127;
        int k4 = e2 >> 9;
        w1q[e2] = w1[n * D_DIM + k4 * 4 + i];
    } else {
        // w1p transpose: e = (k4*256+j)*4+i
        int e  = id - 196608;
        int i  = e & 3;
        int j  = (e >> 2) & 255;
        int k4 = e >> 10;
        w1p[e] = pw1[j * D_DIM + k4 * 4 + i];
    }
}

// ===========================================================================
// K1: approx scores. 1024 blocks x 256 threads (4 waves, 32 rows each).
//     B-frags: global -> LDS (dbuf) via global_load_lds; A: registers.
// ===========================================================================
__device__ inline void split8(float4 a, float4 b, bf16x8& hi, bf16x8& lo) {
    float v[8] = {a.x, a.y, a.z, a.w, b.x, b.y, b.z, b.w};
#pragma unroll
    for (int i = 0; i < 8; ++i) {
        __bf16 h = (__bf16)v[i];
        hi[i] = h;
        lo[i] = (__bf16)(v[i] - (float)h);
    }
}

__global__ __launch_bounds__(256, 4) void score_mfma(
    const float*  __restrict__ th,    // [131072, 768]
    const __bf16* __restrict__ whi,   // B-frags hi
    const __bf16* __restrict__ wlo,   // B-frags lo
    const float*  __restrict__ b1,    // [128]
    const float*  __restrict__ w2,    // [128]
    float* __restrict__ scores)       // [131072]
{
    // [buf][hi/lo][nt*512 + lane*8] : 2*2*4096 bf16 = 32 KB
    __shared__ __bf16 Bs[2][2][8 * 512];

    const int tid = threadIdx.x;
    const int wv  = tid >> 6;
    const int ln  = tid & 63;

    const size_t row0 = (size_t)blockIdx.x * 128 + wv * 32 + (ln & 15);
    const float* pa0 = th + row0 * D_DIM + (ln >> 4) * 8;
    const float* pa1 = pa0 + 16 * D_DIM;

    // wave wv stages segments {wv, wv+4, wv+8, wv+12}; seg<8: hi nt=seg,
    // else lo nt=seg-8. Each segment: 64 lanes x 16 B = 1 KB (one nt frag).
    auto stage = [&](int kt, int buf) {
#pragma unroll
        for (int q = 0; q < 4; ++q) {
            int s  = wv + q * 4;
            int hl = s >> 3;
            int nt = s & 7;
            const __bf16* src = (hl ? wlo : whi) +
                                (((size_t)nt * 24 + kt) * 64 + ln) * 8;
            __bf16* dst = &Bs[buf][hl][nt * 512];  // wave-uniform base
            __builtin_amdgcn_global_load_lds(
                (GLOBAL_AS const void*)src, (LDS_AS void*)dst, 16, 0, 0);
        }
    };

    f32x4 acc[2][8];
    const f32x4 z = {0.f, 0.f, 0.f, 0.f};
#pragma unroll
    for (int i = 0; i < 2; ++i)
#pragma unroll
        for (int j = 0; j < 8; ++j) acc[i][j] = z;

    float4 c00 = *(const float4*)(pa0);
    float4 c01 = *(const float4*)(pa0 + 4);
    float4 c10 = *(const float4*)(pa1);
    float4 c11 = *(const float4*)(pa1 + 4);
    stage(0, 0);
    __syncthreads();   // buf0 staged (barrier drains vmcnt)

    for (int kt = 0; kt < 24; ++kt) {
        const int buf = kt & 1;
        float4 n00, n01, n10, n11;
        if (kt < 23) {
            n00 = *(const float4*)(pa0 + (kt + 1) * 32);
            n01 = *(const float4*)(pa0 + (kt + 1) * 32 + 4);
            n10 = *(const float4*)(pa1 + (kt + 1) * 32);
            n11 = *(const float4*)(pa1 + (kt + 1) * 32 + 4);
            stage(kt + 1, buf ^ 1);
        }

        bf16x8 ah0, al0, ah1, al1;
        split8(c00, c01, ah0, al0);
        split8(c10, c11, ah1, al1);

#pragma unroll
        for (int nt = 0; nt < 8; ++nt) {
            bf16x8 bh = *(bf16x8*)(&Bs[buf][0][nt * 512 + ln * 8]);
            bf16x8 bl = *(bf16x8*)(&Bs[buf][1][nt * 512 + ln * 8]);
            acc[0][nt] = __builtin_amdgcn_mfma_f32_16x16x32_bf16(ah0, bh, acc[0][nt], 0, 0, 0);
            acc[0][nt] = __builtin_amdgcn_mfma_f32_16x16x32_bf16(al0, bh, acc[0][nt], 0, 0, 0);
            acc[0][nt] = __builtin_amdgcn_mfma_f32_16x16x32_bf16(ah0, bl, acc[0][nt], 0, 0, 0);
            acc[1][nt] = __builtin_amdgcn_mfma_f32_16x16x32_bf16(ah1, bh, acc[1][nt], 0, 0, 0);
            acc[1][nt] = __builtin_amdgcn_mfma_f32_16x16x32_bf16(al1, bh, acc[1][nt], 0, 0, 0);
            acc[1][nt] = __builtin_amdgcn_mfma_f32_16x16x32_bf16(ah1, bl, acc[1][nt], 0, 0, 0);
        }
        if (kt < 23) {
            c00 = n00; c01 = n01; c10 = n10; c11 = n11;
            __syncthreads();   // drains stage(kt+1); gates buf reuse
        }
    }

    // epilogue: s = sum_n tanh(pre + b1[n]) * w2[n]; reduce over the 16 cols
    const int col = ln & 15;
    float b1v[8], w2v[8];
#pragma unroll
    for (int nt = 0; nt < 8; ++nt) {
        b1v[nt] = b1[nt * 16 + col];
        w2v[nt] = w2[nt * 16 + col];
    }
    const size_t rowbase = (size_t)blockIdx.x * 128 + wv * 32;
#pragma unroll
    for (int mf = 0; mf < 2; ++mf)
#pragma unroll
        for (int r = 0; r < 4; ++r) {
            float s = 0.f;
#pragma unroll
            for (int nt = 0; nt < 8; ++nt)
                s += tanhf(acc[mf][nt][r] + b1v[nt]) * w2v[nt];
            s += __shfl_xor(s, 1, 64);
            s += __shfl_xor(s, 2, 64);
            s += __shfl_xor(s, 4, 64);
            s += __shfl_xor(s, 8, 64);
            if (col == 0)
                scores[rowbase + mf * 16 + (ln >> 4) * 4 + r] = s;
        }
}

// ===========================================================================
// K2: per batch select + project. 256 blocks x 256 threads.
// ===========================================================================
__global__ __launch_bounds__(256) void select_kernel(
    const float* __restrict__ th,      // [B*S, 768]
    const int*   __restrict__ mask,    // [B*S]
    const float* __restrict__ ascores, // approx scores [B*S]
    const float* __restrict__ w1q,     // k-major att_w1
    const float* __restrict__ ab1,     // att_b1 [128]
    const float* __restrict__ aw2,     // att_w2 [128]
    const float* __restrict__ w1p,     // k-major proj_w1
    const float* __restrict__ pb1,     // proj_b1 [256]
    const float* __restrict__ pw2,     // [5, 256]
    const float* __restrict__ pb2,     // [5]
    const float* __restrict__ gamma,   // [60]
    const float* __restrict__ beta,    // [60]
    float* __restrict__ out)           // [B, 5, 12]
{
    const int b   = blockIdx.x;
    const int tid = threadIdx.x;
    const int wv  = tid >> 6;
    const int ln  = tid & 63;

    __shared__ float4 xc[NCAND][192];          // 48KB candidate rows (fp32)
    __shared__ unsigned long long wtop[64];
    __shared__ int   cand[NCAND];
    __shared__ float redW[4][8];
    __shared__ float exact_sc[NCAND];
    __shared__ int   sel_slot[TOPK];
    __shared__ float gbuf[TOPK][H_PROJ + 4];   // +4 keeps rows 16B-aligned
    __shared__ float feat[N_ROWS * N_COLS];
    __shared__ float stats[2];

    const float NEG_MIN = -3.402823466e38f;    // finfo(float32).min

    // --- barrier-free per-wave top-16 over 128 scores (2 keys/lane) ---
    {
        int i0 = wv * 128 + ln, i1 = i0 + 64;
        float v0 = ascores[(size_t)b * S_LEN + i0];
        if (mask[(size_t)b * S_LEN + i0] == 0) v0 = NEG_MIN;
        float v1 = ascores[(size_t)b * S_LEN + i1];
        if (mask[(size_t)b * S_LEN + i1] == 0) v1 = NEG_MIN;
        unsigned k0 = __float_as_uint(v0);
        k0 = ((int)k0 >= 0) ? (k0 | 0x80000000u) : ~k0;
        unsigned k1 = __float_as_uint(v1);
        k1 = ((int)k1 >= 0) ? (k1 | 0x80000000u) : ~k1;
        unsigned long long p0 = ((unsigned long long)k0 << 32) | (0xFFFFFFFFu - (unsigned)i0);
        unsigned long long p1 = ((unsigned long long)k1 << 32) | (0xFFFFFFFFu - (unsigned)i1);
        for (int it = 0; it < NCAND; ++it) {
            unsigned long long m = p0 > p1 ? p0 : p1;
#pragma unroll
            for (int s = 1; s <= 32; s <<= 1) {
                unsigned long long o = __shfl_xor(m, s, 64);
                if (o > m) m = o;
            }
            if (ln == 0) wtop[wv * 16 + it] = m;
            if (p0 == m) p0 = 0ull;
            else if (p1 == m) p1 = 0ull;
        }
    }
    __syncthreads();
    // --- single-wave merge of 64 keys -> global top-16 ---
    if (wv == 0) {
        unsigned long long q = wtop[ln];
        for (int it = 0; it < NCAND; ++it) {
            unsigned long long m = q;
#pragma unroll
            for (int s = 1; s <= 32; s <<= 1) {
                unsigned long long o = __shfl_xor(m, s, 64);
                if (o > m) m = o;
            }
            if (ln == 0) cand[it] = (int)(0xFFFFFFFFu - (unsigned)(m & 0xFFFFFFFFu));
            if (q == m) q = 0ull;
        }
    }
    __syncthreads();

    // --- stage candidate rows into LDS (fp32, float4) ---
#pragma unroll
    for (int i = 0; i < 12; ++i) {
        int f = tid + 256 * i;             // 0..3071
        int c = f / 192, k4 = f % 192;
        xc[c][k4] = *(const float4*)(th + ((size_t)b * S_LEN + cand[c]) * D_DIM + k4 * 4);
    }
    __syncthreads();

    // --- exact fp32 rescore of 16 candidates ---
    {
        const int n = tid & 127;
        const int h = tid >> 7;
        float accs[8];
#pragma unroll
        for (int ci = 0; ci < 8; ++ci) accs[ci] = 0.f;
        for (int k4 = 0; k4 < 192; ++k4) {
            float4 w = *(const float4*)(w1q + (size_t)(k4 * 128 + n) * 4);
#pragma unroll
            for (int ci = 0; ci < 8; ++ci) {
                float4 x = xc[2 * ci + h][k4];
                accs[ci] += w.x * x.x + w.y * x.y + w.z * x.z + w.w * x.w;
            }
        }
        float b1n = ab1[n], w2n = aw2[n];
#pragma unroll
        for (int ci = 0; ci < 8; ++ci) {
            float val = tanhf(accs[ci] + b1n) * w2n;
            val += __shfl_xor(val, 1, 64);
            val += __shfl_xor(val, 2, 64);
            val += __shfl_xor(val, 4, 64);
            val += __shfl_xor(val, 8, 64);
            val += __shfl_xor(val, 16, 64);
            val += __shfl_xor(val, 32, 64);
            if (ln == 0) redW[wv][ci] = val;
        }
    }
    __syncthreads();
    if (tid < NCAND) {
        int c = tid;
        float ex = (c & 1) ? (redW[2][c >> 1] + redW[3][c >> 1])
                           : (redW[0][c >> 1] + redW[1][c >> 1]);
        if (mask[(size_t)b * S_LEN + cand[c]] == 0) ex = -INFINITY;
        exact_sc[c] = ex;
    }
    __syncthreads();

    // --- exact top-12 among candidates (tie -> smallest token index), sort ---
    if (tid == 0) {
        unsigned picked = 0;
        int slots[TOPK];
        for (int it = 0; it < TOPK; ++it) {
            float best = -INFINITY; int bslot = -1; int bidx = 1 << 30;
            for (int c = 0; c < NCAND; ++c) {
                if (picked & (1u << c)) continue;
                float e = exact_sc[c]; int idx = cand[c];
                if (e > best || (e == best && idx < bidx)) { best = e; bslot = c; bidx = idx; }
            }
            picked |= 1u << bslot;
            slots[it] = bslot;
        }
        for (int i = 1; i < TOPK; ++i) {
            int s = slots[i], key = cand[s], j = i - 1;
            while (j >= 0 && cand[slots[j]] > key) { slots[j + 1] = slots[j]; --j; }
            slots[j + 1] = s;
        }
        for (int t = 0; t < TOPK; ++t) sel_slot[t] = slots[t];
    }
    __syncthreads();

    // --- projector: thread j owns column j; x-reads are LDS broadcasts ---
    {
        const int j = tid;
        int slots[TOPK];
#pragma unroll
        for (int t = 0; t < TOPK; ++t) slots[t] = sel_slot[t];
        float accp[TOPK];
        float bj = pb1[j];
#pragma unroll
        for (int t = 0; t < TOPK; ++t) accp[t] = bj;
        for (int k4 = 0; k4 < 192; ++k4) {
            float4 w = *(const float4*)(w1p + ((size_t)k4 * 256 + j) * 4);
#pragma unroll
            for (int t = 0; t < TOPK; ++t) {
                float4 x = xc[slots[t]][k4];
                accp[t] += w.x * x.x + w.y * x.y + w.z * x.z + w.w * x.w;
            }
        }
#pragma unroll
        for (int t = 0; t < TOPK; ++t) {
            float hh = accp[t];
            gbuf[t][j] = 0.5f * hh * (1.0f + erff(hh * 0.70710678118654752f));
        }
    }
    __syncthreads();

    // --- f @ pw2^T + pb2 ---
    if (tid < TOPK * N_ROWS) {
        int t = tid / N_ROWS, r = tid % N_ROWS;
        float s = pb2[r];
        const float4* gp = (const float4*)&gbuf[t][0];
        const float4* wp = (const float4*)(pw2 + r * H_PROJ);
        for (int q = 0; q < H_PROJ / 4; ++q) {
            float4 g = gp[q], w = wp[q];
            s += g.x * w.x + g.y * w.y + g.z * w.z + g.w * w.w;
        }
        feat[r * N_COLS + t] = s;
    }
    __syncthreads();

    // --- LayerNorm over 60 elements ---
    if (tid == 0) {
        float sum = 0.f;
        for (int i = 0; i < N_ROWS * N_COLS; ++i) sum += feat[i];
        float mean = sum / 60.f;
        float sq = 0.f;
        for (int i = 0; i < N_ROWS * N_COLS; ++i) { float d = feat[i] - mean; sq += d * d; }
        stats[0] = mean;
        stats[1] = sq / 60.f;
    }
    __syncthreads();
    if (tid < N_ROWS * N_COLS) {
        float x = feat[tid];
        out[(size_t)b * 60 + tid] =
            gamma[tid] * (x - stats[0]) * rsqrtf(stats[1] + 1e-5f) + beta[tid];
    }
}

// ===========================================================================
extern "C" void kernel_launch(void* const* d_in, const int* in_sizes, int n_in,
                              void* d_out, int out_size, void* d_ws, size_t ws_size,
                              hipStream_t stream) {
    const float* th   = (const float*)d_in[0];
    const int*   mask = (const int*)  d_in[1];
    const float* aw1  = (const float*)d_in[2];
    const float* ab1  = (const float*)d_in[3];
    const float* aw2  = (const float*)d_in[4];
    // d_in[5] att_b2: constant shift — irrelevant for top-k ordering
    const float* pw1  = (const float*)d_in[6];
    const float* pb1  = (const float*)d_in[7];
    const float* pw2  = (const float*)d_in[8];
    const float* pb2  = (const float*)d_in[9];
    const float* gam  = (const float*)d_in[10];
    const float* bet  = (const float*)d_in[11];
    float* out = (float*)d_out;

    char* ws = (char*)d_ws;
    float*  scores = (float*)(ws + WS_SCORES);
    __bf16* whi    = (__bf16*)(ws + WS_WHI);
    __bf16* wlo    = (__bf16*)(ws + WS_WLO);
    float*  w1q    = (float*)(ws + WS_W1Q);
    float*  w1p    = (float*)(ws + WS_W1P);

    hipLaunchKernelGGL(prep_kernel, dim3(1536), dim3(256), 0, stream,
                       aw1, pw1, whi, wlo, w1q, w1p);
    hipLaunchKernelGGL(score_mfma, dim3(1024), dim3(256), 0, stream,
                       th, whi, wlo, ab1, aw2, scores);
    hipLaunchKernelGGL(select_kernel, dim3(B_BATCH), dim3(256), 0, stream,
                       th, mask, scores, w1q, ab1, aw2,
                       w1p, pb1, pw2, pb2, gam, bet, out);
}